// Round 6
// baseline (403.407 us; speedup 1.0000x reference)
//
#include <hip/hip_runtime.h>
#include <math.h>

#define NB 4
#define NL 2048
#define NH 8
#define ND 64
#define NUPART 80
#define NUTOP 40
#define ZROWS_K1 320          // rows [0,320) per bh zeroed by K1 (80 MiB)
#define NZB_PER_BH 432        // zero blocks per bh in K3: 432*4 rows = [320,2048)
#define NATTN (NB * NH * NUTOP)   // 1280 attn blocks

typedef float vfloat4 __attribute__((ext_vector_type(4)));

// ---------------------------------------------------------------------------
// K1: M[b,h,l] = max_s(q.k_s) - sum_s(q.k_s)/L over 80 sampled keys, fused
// with zero-fill of rows [0,320) of each bh (80 MiB) -- sized so the write
// time (~50 us at the ~1.6 TB/s d_out cap) just covers the gather time.
// 16384 blocks = 32 bh x 512 slices; slice = 320 float4.
// ---------------------------------------------------------------------------
__global__ __launch_bounds__(256) void k_compute_M_zero(
    const float* __restrict__ q, const float* __restrict__ k,
    const int* __restrict__ idx, float* __restrict__ M,
    float* __restrict__ out)
{
    const int t = threadIdx.x;

    // ---- zero slice: bh = blockIdx>>9 owns f4 range [j*320, j*320+320) of
    //      its row-region [0,320) (= f4 indices [0, 163840)) ----
    {
        const int bhz = blockIdx.x >> 9;
        const int j   = blockIdx.x & 511;
        vfloat4* o = (vfloat4*)out + (size_t)bhz * (NL * NL / 4) + j * 320 + t;
        const vfloat4 z = (vfloat4)(0.0f);
        o[0] = z;                    // 256
        if (t < 64) o[256] = z;      // + 64 = 320
    }

    // ---- M computation: one wave per (b,h,l) ----
    const int w    = blockIdx.x * 4 + (t >> 6);   // (b*H+h)*L + l
    const int lane = t & 63;
    const int l    = w & (NL - 1);
    const int bh   = w >> 11;
    const int h    = bh & (NH - 1);
    const int b    = bh >> 3;
    const int sl   = lane >> 2;   // 0..15 sample slot
    const int dg   = lane & 3;    // 0..3 d-group
    const int d0   = dg * 16;

    const float4* qv = (const float4*)(q + (((size_t)(b * NL + l) * NH + h) * ND + d0));
    const float4 q0 = qv[0], q1 = qv[1], q2 = qv[2], q3 = qv[3];

    float mx = -INFINITY, sm = 0.0f;
#pragma unroll
    for (int r = 0; r < 5; ++r) {
        const int s  = r * 16 + sl;
        const int ki = idx[l * NUPART + s];
        const float4* kv = (const float4*)(k + (((size_t)(b * NL + ki) * NH + h) * ND + d0));
        const float4 k0 = kv[0], k1 = kv[1], k2 = kv[2], k3 = kv[3];
        float p = q0.x * k0.x + q0.y * k0.y + q0.z * k0.z + q0.w * k0.w
                + q1.x * k1.x + q1.y * k1.y + q1.z * k1.z + q1.w * k1.w
                + q2.x * k2.x + q2.y * k2.y + q2.z * k2.z + q2.w * k2.w
                + q3.x * k3.x + q3.y * k3.y + q3.z * k3.z + q3.w * k3.w;
        p += __shfl_xor(p, 1);
        p += __shfl_xor(p, 2);
        mx = fmaxf(mx, p);
        sm += p;
    }
#pragma unroll
    for (int m = 4; m < 64; m <<= 1) {
        mx = fmaxf(mx, __shfl_xor(mx, m));
        sm += __shfl_xor(sm, m);
    }
    if (lane == 0) M[w] = mx - sm * (1.0f / (float)NL);
}

// ---------------------------------------------------------------------------
// K2: per (b,h), top-40 of 2048 M values (iterative argmax, lower index
// wins ties). Emits the index list (Mtop) and a per-row flag (rowmap).
// ---------------------------------------------------------------------------
__global__ __launch_bounds__(256) void k_topk(
    const float* __restrict__ M, int* __restrict__ rowmap,
    int* __restrict__ Mtop)
{
    __shared__ float sM[NL];
    __shared__ float rv[4];
    __shared__ int   ri[4];
    const int bh = blockIdx.x;
    const int t  = threadIdx.x;

    for (int j = t; j < NL; j += 256) {
        sM[j] = M[bh * NL + j];
        rowmap[bh * NL + j] = 0;
    }
    __syncthreads();

    for (int it = 0; it < NUTOP; ++it) {
        float v = -INFINITY;
        int   i = NL;
        for (int j = t; j < NL; j += 256) {
            const float m = sM[j];
            if (m > v || (m == v && j < i)) { v = m; i = j; }
        }
#pragma unroll
        for (int off = 1; off < 64; off <<= 1) {
            const float ov = __shfl_xor(v, off);
            const int   oi = __shfl_xor(i, off);
            if (ov > v || (ov == v && oi < i)) { v = ov; i = oi; }
        }
        const int wid = t >> 6;
        if ((t & 63) == 0) { rv[wid] = v; ri[wid] = i; }
        __syncthreads();
        if (t == 0) {
            for (int w2 = 1; w2 < 4; ++w2) {
                if (rv[w2] > v || (rv[w2] == v && ri[w2] < i)) { v = rv[w2]; i = ri[w2]; }
            }
            Mtop[bh * NUTOP + it] = i;
            rowmap[bh * NL + i] = 1;
            sM[i] = -INFINITY;
        }
        __syncthreads();
    }
}

// ---------------------------------------------------------------------------
// K3: heterogeneous launch. Blocks [0,1280): one per selected row --
// q_row.K^T -> softmax -> write attn row. Blocks [1280, 1280+13824): zero
// 4 rows each of the per-bh region [320,2048), skipping selected rows
// (those are attn-written; skip avoids intra-kernel write races).
// Attn compute (and its L2/L3 K reads) hides inside the ~430 MiB zero
// write tide, which runs at the d_out write cap.
// ---------------------------------------------------------------------------
__global__ __launch_bounds__(256) void k_attn_zero(
    const float* __restrict__ q, const float* __restrict__ k,
    const int* __restrict__ rowmap, const int* __restrict__ Mtop,
    float* __restrict__ out)
{
    const int t = threadIdx.x;

    if (blockIdx.x >= NATTN) {
        // ---- zero block: 4 rows of bh's region [320,2048) ----
        const int zb = blockIdx.x - NATTN;
        const int bh = zb / NZB_PER_BH;
        const int ri = zb - bh * NZB_PER_BH;
        const int r0 = ZROWS_K1 + ri * 4;
        const vfloat4 z = (vfloat4)(0.0f);
#pragma unroll
        for (int rr = 0; rr < 4; ++rr) {
            const int r = r0 + rr;
            if (rowmap[bh * NL + r]) continue;   // attn writes this row
            vfloat4* o = (vfloat4*)out + ((size_t)bh * NL + r) * (NL / 4) + t;
            o[0]   = z;
            o[256] = z;
        }
        return;
    }

    // ---- attn block: one selected row ----
    const int bh  = blockIdx.x / NUTOP;
    const int ui  = blockIdx.x % NUTOP;
    const int b   = bh >> 3;
    const int h   = bh & 7;
    const int row = Mtop[bh * NUTOP + ui];

    __shared__ float redm[4];
    __shared__ float reds[4];
    const int lane = t & 63;
    const int wid  = t >> 6;

    // q row is wave-uniform: broadcast loads, kept in registers
    const float4* qv = (const float4*)(q + (((size_t)(b * NL + row)) * NH + h) * ND);
    float4 qr[16];
#pragma unroll
    for (int i = 0; i < 16; ++i) qr[i] = qv[i];

    float sc[8];
    float mx = -INFINITY;
#pragma unroll
    for (int j = 0; j < 8; ++j) {
        const int l = t + 256 * j;
        const float4* kv = (const float4*)(k + (((size_t)(b * NL + l)) * NH + h) * ND);
        float s = 0.0f;
#pragma unroll
        for (int i = 0; i < 16; ++i) {
            const float4 kk = kv[i];
            s += qr[i].x * kk.x + qr[i].y * kk.y + qr[i].z * kk.z + qr[i].w * kk.w;
        }
        sc[j] = s * 0.125f;   // 1/sqrt(64)
        mx = fmaxf(mx, sc[j]);
    }

#pragma unroll
    for (int off = 1; off < 64; off <<= 1) mx = fmaxf(mx, __shfl_xor(mx, off));
    if (lane == 0) redm[wid] = mx;
    __syncthreads();
    mx = fmaxf(fmaxf(redm[0], redm[1]), fmaxf(redm[2], redm[3]));

    float lsum = 0.0f;
#pragma unroll
    for (int j = 0; j < 8; ++j) {
        sc[j] = __expf(sc[j] - mx);
        lsum += sc[j];
    }
#pragma unroll
    for (int off = 1; off < 64; off <<= 1) lsum += __shfl_xor(lsum, off);
    if (lane == 0) reds[wid] = lsum;
    __syncthreads();
    const float inv = 1.0f / (reds[0] + reds[1] + reds[2] + reds[3]);

    float* orow = out + ((size_t)bh * NL + row) * NL;
#pragma unroll
    for (int j = 0; j < 8; ++j) {
        orow[t + 256 * j] = sc[j] * inv;
    }
}

extern "C" void kernel_launch(void* const* d_in, const int* in_sizes, int n_in,
                              void* d_out, int out_size, void* d_ws, size_t ws_size,
                              hipStream_t stream) {
    const float* q   = (const float*)d_in[0];
    const float* k   = (const float*)d_in[1];
    const int*   idx = (const int*)d_in[2];
    float* out = (float*)d_out;

    float* Mws    = (float*)d_ws;                                     // 65536 f
    int*   rowmap = (int*)((char*)d_ws + (size_t)NB * NH * NL * 4);   // 65536 i
    int*   Mtop   = (int*)((char*)d_ws + (size_t)NB * NH * NL * 8);   // 1280 i

    k_compute_M_zero<<<NB * NH * NL / 4, 256, 0, stream>>>(q, k, idx, Mws, out);
    k_topk<<<NB * NH, 256, 0, stream>>>(Mws, rowmap, Mtop);
    k_attn_zero<<<NATTN + NB * NH * NZB_PER_BH, 256, 0, stream>>>(q, k, rowmap, Mtop, out);
}